// Round 3
// baseline (974.938 us; speedup 1.0000x reference)
//
#include <hip/hip_runtime.h>
#include <stdint.h>

#define EMBED 128
#define HIDDEN 256

typedef __bf16 v8bf __attribute__((ext_vector_type(8)));
typedef float v4f __attribute__((ext_vector_type(4)));

__device__ __forceinline__ float bf2f(unsigned short u){
    union { uint32_t i; float f; } v; v.i = ((uint32_t)u) << 16; return v.f;
}
__device__ __forceinline__ unsigned short f2bf(float f){
    union { float f; uint32_t i; } v; v.f = f;
    uint32_t i = v.i;
    uint32_t r = (i + 0x7fffu + ((i >> 16) & 1u)) >> 16;
    return (unsigned short)r;
}
__device__ __forceinline__ float lo_f(uint32_t u){ union{uint32_t i;float f;}v; v.i=u<<16; return v.f; }
__device__ __forceinline__ float hi_f(uint32_t u){ union{uint32_t i;float f;}v; v.i=u&0xffff0000u; return v.f; }
__device__ __forceinline__ uint32_t pack2(float a, float b){
    return (uint32_t)f2bf(a) | ((uint32_t)f2bf(b) << 16);
}
__device__ __forceinline__ float silu_f(float x){ return x / (1.0f + __expf(-x)); }

// scalar dtype-polymorphic load
__device__ __forceinline__ float loadf(const void* b, size_t i, int isf32){
    return isf32 ? ((const float*)b)[i] : bf2f(((const unsigned short*)b)[i]);
}
// 8-wide dtype-polymorphic load (16B/32B vector loads)
__device__ __forceinline__ void load8f(const void* base, size_t off, int isf32, float o[8]){
    if (isf32){
        const float* p = (const float*)base + off;
        float4 a = *(const float4*)p, b = *(const float4*)(p + 4);
        o[0]=a.x;o[1]=a.y;o[2]=a.z;o[3]=a.w;o[4]=b.x;o[5]=b.y;o[6]=b.z;o[7]=b.w;
    } else {
        uint4 v = *(const uint4*)((const unsigned short*)base + off);
        uint32_t w[4] = {v.x, v.y, v.z, v.w};
        #pragma unroll
        for (int q = 0; q < 4; q++){ o[2*q] = lo_f(w[q]); o[2*q+1] = hi_f(w[q]); }
    }
}
__device__ __forceinline__ int idx_c(const int* ei, int e, int is64){
    return is64 ? ei[2*(size_t)e] : ei[e];
}
__device__ __forceinline__ int idx_n(const int* ei, int e, int E, int is64){
    return is64 ? ei[2*((size_t)E + e)] : ei[(size_t)E + e];
}

// ---------------- Runtime dtype probe ----------------
// flags[0]=1 if float arrays are fp32 (bf16 interp of N(0,1) data shows huge/NaN halves)
// flags[1]=1 if edge_index_list is int64 (odd 32-bit words of first 128 pairs all zero)
__global__ __launch_bounds__(256) void probe_kernel(
    const unsigned short* __restrict__ ne, const int* __restrict__ ei, int* __restrict__ flags)
{
    __shared__ int s_badf, s_nzidx;
    if (threadIdx.x == 0){ s_badf = 0; s_nzidx = 0; }
    __syncthreads();
    int t = threadIdx.x;
    int bad = 0;
    #pragma unroll
    for (int i = 0; i < 16; i++){
        unsigned short u = ne[t * 16 + i];
        int ex = (u >> 7) & 0xFF;
        if (ex >= 0x85) bad = 1;      // |x| >= 64 or inf/nan: impossible for bf16 N(0,1)
    }
    if (bad) atomicOr(&s_badf, 1);
    if (t < 128 && ei[2 * t + 1] != 0) atomicOr(&s_nzidx, 1);
    __syncthreads();
    if (threadIdx.x == 0){ flags[0] = s_badf; flags[1] = s_nzidx ? 0 : 1; }
}

// ---------------- LayerNorm: one wave per node, h stored bf16 ----------------
__global__ __launch_bounds__(256) void ln_kernel(
    const void* __restrict__ x, const void* __restrict__ g, const void* __restrict__ b,
    unsigned short* __restrict__ h, int N, const int* __restrict__ flags)
{
    int isf32 = flags[0];
    int wave = threadIdx.x >> 6, lane = threadIdx.x & 63;
    int node = blockIdx.x * 4 + wave;
    if (node >= N) return;
    float x0, x1;
    if (isf32){
        float2 v = *(const float2*)((const float*)x + (size_t)node * EMBED + lane * 2);
        x0 = v.x; x1 = v.y;
    } else {
        uint32_t u = *(const uint32_t*)((const unsigned short*)x + (size_t)node * EMBED + lane * 2);
        x0 = lo_f(u); x1 = hi_f(u);
    }
    float s = x0 + x1, ss = x0 * x0 + x1 * x1;
    for (int m = 1; m < 64; m <<= 1){ s += __shfl_xor(s, m); ss += __shfl_xor(ss, m); }
    float mean = s * (1.0f / EMBED);
    float var  = ss * (1.0f / EMBED) - mean * mean;
    float rs   = rsqrtf(var + 1e-5f);
    float g0 = loadf(g, lane * 2, isf32), g1 = loadf(g, lane * 2 + 1, isf32);
    float b0 = loadf(b, lane * 2, isf32), b1v = loadf(b, lane * 2 + 1, isf32);
    float y0 = (x0 - mean) * rs * g0 + b0;
    float y1 = (x1 - mean) * rs * g1 + b1v;
    *(uint32_t*)(h + (size_t)node * EMBED + lane * 2) = pack2(y0, y1);
}

// ---------------- Weight + bias prepack into MFMA B-frag order (bf16) ----------------
__global__ __launch_bounds__(256) void prepack_kernel(
    const void* __restrict__ W1, const void* __restrict__ W2, const void* __restrict__ Wt,
    const void* __restrict__ b1, const void* __restrict__ b2, const void* __restrict__ bt,
    unsigned short* __restrict__ W1p, unsigned short* __restrict__ W2p,
    unsigned short* __restrict__ Wtp, unsigned short* __restrict__ bpk,
    const int* __restrict__ flags)
{
    int isf32 = flags[0];
    int t = blockIdx.x * blockDim.x + threadIdx.x;
    if (t < 32768){            // W1: [128][256], 16 ntiles x 4 k32
        int j = t & 7, lane = (t >> 3) & 63, k32 = (t >> 9) & 3, nt = t >> 11;
        int k = k32 * 32 + (lane >> 4) * 8 + j, n = nt * 16 + (lane & 15);
        W1p[t] = f2bf(loadf(W1, (size_t)k * HIDDEN + n, isf32));
    } else if (t < 65536){     // W2: [256][128], 8 ntiles x 8 k32
        int t2 = t - 32768;
        int j = t2 & 7, lane = (t2 >> 3) & 63, k32 = (t2 >> 9) & 7, nt = t2 >> 12;
        int k = k32 * 32 + (lane >> 4) * 8 + j, n = nt * 16 + (lane & 15);
        W2p[t2] = f2bf(loadf(W2, (size_t)k * EMBED + n, isf32));
    } else if (t < 81920){     // Wt: [128][128], 8 ntiles x 4 k32
        int t3 = t - 65536;
        int j = t3 & 7, lane = (t3 >> 3) & 63, k32 = (t3 >> 9) & 3, nt = t3 >> 11;
        int k = k32 * 32 + (lane >> 4) * 8 + j, n = nt * 16 + (lane & 15);
        Wtp[t3] = f2bf(loadf(Wt, (size_t)k * EMBED + n, isf32));
    } else if (t < 82176){     // b1 [256]
        int i = t - 81920; bpk[i] = f2bf(loadf(b1, i, isf32));
    } else if (t < 82304){     // b2 [128]
        int i = t - 82176; bpk[256 + i] = f2bf(loadf(b2, i, isf32));
    } else if (t < 82432){     // bt [128]
        int i = t - 82304; bpk[384 + i] = f2bf(loadf(bt, i, isf32));
    }
}

// ---------------- Edge MLP: 1 wave = 16 edges, MFMA 16x16x32 ----------------
__global__ __launch_bounds__(256) void edge_kernel(
    const void* __restrict__ ee, const unsigned short* __restrict__ h,
    const int* __restrict__ eidx, int E,
    const unsigned short* __restrict__ W1p, const unsigned short* __restrict__ W2p,
    const unsigned short* __restrict__ bpk,
    float* __restrict__ agg, const int* __restrict__ flags)
{
    __shared__ __align__(16) unsigned short sbuf[4][16][136]; // silu(s) [16 x 128]
    __shared__ __align__(16) unsigned short tbuf[4][16][264]; // silu(t) [16 x 256]
    int isf32 = flags[0], is64 = flags[1];
    int wave = threadIdx.x >> 6, lane = threadIdx.x & 63;
    int quad = lane >> 4, l16 = lane & 15;
    int ebase = (blockIdx.x * 4 + wave) * 16;
    int colg = l16 * 8;

    // stage silu(edge + h_c + h_n) -> sbuf
    #pragma unroll
    for (int i = 0; i < 4; i++){
        int row = i * 4 + quad;
        int e = ebase + row; if (e >= E) e = E - 1;
        int c = idx_c(eidx, e, is64), n = idx_n(eidx, e, E, is64);
        float fe[8];
        load8f(ee, (size_t)e * EMBED + colg, isf32, fe);
        uint4 vc = *(const uint4*)(h + (size_t)c * EMBED + colg);
        uint4 vn = *(const uint4*)(h + (size_t)n * EMBED + colg);
        uint32_t pc[4] = {vc.x, vc.y, vc.z, vc.w};
        uint32_t pn[4] = {vn.x, vn.y, vn.z, vn.w};
        uint32_t o[4];
        #pragma unroll
        for (int q = 0; q < 4; q++){
            float a0 = fe[2*q]   + lo_f(pc[q]) + lo_f(pn[q]);
            float a1 = fe[2*q+1] + hi_f(pc[q]) + hi_f(pn[q]);
            o[q] = pack2(silu_f(a0), silu_f(a1));
        }
        *(uint4*)&sbuf[wave][row][colg] = make_uint4(o[0], o[1], o[2], o[3]);
    }
    __syncthreads();  // cross-lane LDS handoff

    // GEMM1: t = silu(s) @ W1 + b1 ; silu(t) -> tbuf
    for (int nt = 0; nt < 16; nt++){
        int col = nt * 16 + l16;
        float bc = bf2f(bpk[col]);
        v4f acc = {bc, bc, bc, bc};
        #pragma unroll
        for (int k32 = 0; k32 < 4; k32++){
            v8bf a = *(const v8bf*)&sbuf[wave][l16][k32 * 32 + quad * 8];
            v8bf b = *(const v8bf*)(W1p + ((size_t)(nt * 4 + k32) * 64 + lane) * 8);
            acc = __builtin_amdgcn_mfma_f32_16x16x32_bf16(a, b, acc, 0, 0, 0);
        }
        #pragma unroll
        for (int r = 0; r < 4; r++)
            tbuf[wave][quad * 4 + r][col] = f2bf(silu_f(acc[r]));
    }
    __syncthreads();  // tbuf produce -> consume

    int c4[4], n4[4];
    #pragma unroll
    for (int r = 0; r < 4; r++){
        int e = ebase + quad * 4 + r;
        int ec = e < E ? e : E - 1;
        c4[r] = idx_c(eidx, ec, is64); n4[r] = idx_n(eidx, ec, E, is64);
    }

    // GEMM2: theta = silu(t) @ W2 + b2 ; msg = h_n * theta -> atomic agg
    for (int nt = 0; nt < 8; nt++){
        int col = nt * 16 + l16;
        float bc = bf2f(bpk[256 + col]);
        v4f acc = {bc, bc, bc, bc};
        #pragma unroll
        for (int k32 = 0; k32 < 8; k32++){
            v8bf a = *(const v8bf*)&tbuf[wave][l16][k32 * 32 + quad * 8];
            v8bf b = *(const v8bf*)(W2p + ((size_t)(nt * 8 + k32) * 64 + lane) * 8);
            acc = __builtin_amdgcn_mfma_f32_16x16x32_bf16(a, b, acc, 0, 0, 0);
        }
        #pragma unroll
        for (int r = 0; r < 4; r++){
            int e = ebase + quad * 4 + r;
            if (e < E){
                float hn = bf2f(h[(size_t)n4[r] * EMBED + col]);
                atomicAdd(&agg[(size_t)c4[r] * EMBED + col], acc[r] * hn);
            }
        }
    }
}

// ---------------- Node output: out = silu(h + agg) @ Wt + bt ----------------
__global__ __launch_bounds__(256) void node_out_kernel(
    const unsigned short* __restrict__ h, const float* __restrict__ agg,
    const unsigned short* __restrict__ Wtp, const unsigned short* __restrict__ bpk,
    void* __restrict__ out, int N, const int* __restrict__ flags)
{
    __shared__ __align__(16) unsigned short ubuf[4][16][136];
    int isf32 = flags[0];
    int wave = threadIdx.x >> 6, lane = threadIdx.x & 63;
    int quad = lane >> 4, l16 = lane & 15;
    int nbase = (blockIdx.x * 4 + wave) * 16;
    int colg = l16 * 8;
    #pragma unroll
    for (int i = 0; i < 4; i++){
        int row = i * 4 + quad;
        int node = nbase + row; int nn = node < N ? node : N - 1;
        uint4 vh = *(const uint4*)(h + (size_t)nn * EMBED + colg);
        float4 a0 = *(const float4*)(agg + (size_t)nn * EMBED + colg);
        float4 a1 = *(const float4*)(agg + (size_t)nn * EMBED + colg + 4);
        uint32_t ph[4] = {vh.x, vh.y, vh.z, vh.w};
        float af[8] = {a0.x, a0.y, a0.z, a0.w, a1.x, a1.y, a1.z, a1.w};
        uint32_t o[4];
        #pragma unroll
        for (int q = 0; q < 4; q++){
            float u0 = lo_f(ph[q]) + af[2 * q];
            float u1 = hi_f(ph[q]) + af[2 * q + 1];
            o[q] = pack2(silu_f(u0), silu_f(u1));
        }
        *(uint4*)&ubuf[wave][row][colg] = make_uint4(o[0], o[1], o[2], o[3]);
    }
    __syncthreads();  // ubuf produce -> consume
    for (int nt = 0; nt < 8; nt++){
        int col = nt * 16 + l16;
        float bc = bf2f(bpk[384 + col]);
        v4f acc = {bc, bc, bc, bc};
        #pragma unroll
        for (int k32 = 0; k32 < 4; k32++){
            v8bf a = *(const v8bf*)&ubuf[wave][l16][k32 * 32 + quad * 8];
            v8bf b = *(const v8bf*)(Wtp + ((size_t)(nt * 4 + k32) * 64 + lane) * 8);
            acc = __builtin_amdgcn_mfma_f32_16x16x32_bf16(a, b, acc, 0, 0, 0);
        }
        #pragma unroll
        for (int r = 0; r < 4; r++){
            int node = nbase + quad * 4 + r;
            if (node < N){
                if (isf32) ((float*)out)[(size_t)node * EMBED + col] = acc[r];
                else ((unsigned short*)out)[(size_t)node * EMBED + col] = f2bf(acc[r]);
            }
        }
    }
}

extern "C" void kernel_launch(void* const* d_in, const int* in_sizes, int n_in,
                              void* d_out, int out_size, void* d_ws, size_t ws_size,
                              hipStream_t stream)
{
    const void* ne = d_in[0];
    const void* ee = d_in[1];
    const int* eidx = (const int*)d_in[2];
    const void* g  = d_in[3];
    const void* be = d_in[4];
    const void* W1 = d_in[5];
    const void* b1 = d_in[6];
    const void* W2 = d_in[7];
    const void* b2 = d_in[8];
    const void* Wt = d_in[9];
    const void* bt = d_in[10];
    int N = in_sizes[0] / EMBED;   // 50000
    int E = in_sizes[2] / 2;       // 640000

    char* ws = (char*)d_ws;
    int* flags = (int*)ws;                                    // 2 ints (pad to 256)
    unsigned short* h = (unsigned short*)(ws + 256);          // N*128 bf16
    size_t off1 = 256 + (size_t)N * EMBED * 2;                // 12,800,256 (256-aligned)
    float* agg = (float*)(ws + off1);                         // N*128 f32
    size_t off2 = off1 + (size_t)N * EMBED * 4;               // 38,400,256 (256-aligned)
    unsigned short* W1p = (unsigned short*)(ws + off2);       // 32768 bf16
    unsigned short* W2p = W1p + 32768;                        // 32768 bf16
    unsigned short* Wtp = W2p + 32768;                        // 16384 bf16
    unsigned short* bpk = Wtp + 16384;                        // 512  bf16

    probe_kernel<<<1, 256, 0, stream>>>((const unsigned short*)ne, eidx, flags);
    hipMemsetAsync(agg, 0, (size_t)N * EMBED * sizeof(float), stream);
    prepack_kernel<<<(82432 + 255) / 256, 256, 0, stream>>>(W1, W2, Wt, b1, b2, bt,
                                                            W1p, W2p, Wtp, bpk, flags);
    ln_kernel<<<(N + 3) / 4, 256, 0, stream>>>(ne, g, be, h, N, flags);
    edge_kernel<<<(E + 63) / 64, 256, 0, stream>>>(ee, h, eidx, E,
                                                   W1p, W2p, bpk, agg, flags);
    node_out_kernel<<<(N + 63) / 64, 256, 0, stream>>>(h, agg, Wtp, bpk,
                                                       d_out, N, flags);
}

// Round 4
// 856.975 us; speedup vs baseline: 1.1377x; 1.1377x over previous
//
#include <hip/hip_runtime.h>
#include <stdint.h>

#define EMBED 128
#define HIDDEN 256

typedef __bf16 v8bf __attribute__((ext_vector_type(8)));
typedef float v4f __attribute__((ext_vector_type(4)));

__device__ __forceinline__ float bf2f(unsigned short u){
    union { uint32_t i; float f; } v; v.i = ((uint32_t)u) << 16; return v.f;
}
__device__ __forceinline__ unsigned short f2bf(float f){
    union { float f; uint32_t i; } v; v.f = f;
    uint32_t i = v.i;
    uint32_t r = (i + 0x7fffu + ((i >> 16) & 1u)) >> 16;
    return (unsigned short)r;
}
__device__ __forceinline__ float lo_f(uint32_t u){ union{uint32_t i;float f;}v; v.i=u<<16; return v.f; }
__device__ __forceinline__ float hi_f(uint32_t u){ union{uint32_t i;float f;}v; v.i=u&0xffff0000u; return v.f; }
__device__ __forceinline__ uint32_t pack2(float a, float b){
    return (uint32_t)f2bf(a) | ((uint32_t)f2bf(b) << 16);
}
__device__ __forceinline__ float silu_f(float x){ return x / (1.0f + __expf(-x)); }

__device__ __forceinline__ float loadf(const void* b, size_t i, int isf32){
    return isf32 ? ((const float*)b)[i] : bf2f(((const unsigned short*)b)[i]);
}
__device__ __forceinline__ void load8f(const void* base, size_t off, int isf32, float o[8]){
    if (isf32){
        const float* p = (const float*)base + off;
        float4 a = *(const float4*)p, b = *(const float4*)(p + 4);
        o[0]=a.x;o[1]=a.y;o[2]=a.z;o[3]=a.w;o[4]=b.x;o[5]=b.y;o[6]=b.z;o[7]=b.w;
    } else {
        uint4 v = *(const uint4*)((const unsigned short*)base + off);
        uint32_t w[4] = {v.x, v.y, v.z, v.w};
        #pragma unroll
        for (int q = 0; q < 4; q++){ o[2*q] = lo_f(w[q]); o[2*q+1] = hi_f(w[q]); }
    }
}
__device__ __forceinline__ int idx_c(const int* ei, int e, int is64){
    return is64 ? ei[2*(size_t)e] : ei[e];
}
__device__ __forceinline__ int idx_n(const int* ei, int e, int E, int is64){
    return is64 ? ei[2*((size_t)E + e)] : ei[(size_t)E + e];
}

// ---------------- Runtime dtype probe ----------------
__global__ __launch_bounds__(256) void probe_kernel(
    const unsigned short* __restrict__ ne, const int* __restrict__ ei, int* __restrict__ flags)
{
    __shared__ int s_badf, s_nzidx;
    if (threadIdx.x == 0){ s_badf = 0; s_nzidx = 0; }
    __syncthreads();
    int t = threadIdx.x;
    int bad = 0;
    #pragma unroll
    for (int i = 0; i < 16; i++){
        unsigned short u = ne[t * 16 + i];
        int ex = (u >> 7) & 0xFF;
        if (ex >= 0x85) bad = 1;      // impossible for bf16 N(0,1)
    }
    if (bad) atomicOr(&s_badf, 1);
    if (t < 128 && ei[2 * t + 1] != 0) atomicOr(&s_nzidx, 1);
    __syncthreads();
    if (threadIdx.x == 0){ flags[0] = s_badf; flags[1] = s_nzidx ? 0 : 1; }
}

// ---------------- LayerNorm ----------------
__global__ __launch_bounds__(256) void ln_kernel(
    const void* __restrict__ x, const void* __restrict__ g, const void* __restrict__ b,
    unsigned short* __restrict__ h, int N, const int* __restrict__ flags)
{
    int isf32 = flags[0];
    int wave = threadIdx.x >> 6, lane = threadIdx.x & 63;
    int node = blockIdx.x * 4 + wave;
    if (node >= N) return;
    float x0, x1;
    if (isf32){
        float2 v = *(const float2*)((const float*)x + (size_t)node * EMBED + lane * 2);
        x0 = v.x; x1 = v.y;
    } else {
        uint32_t u = *(const uint32_t*)((const unsigned short*)x + (size_t)node * EMBED + lane * 2);
        x0 = lo_f(u); x1 = hi_f(u);
    }
    float s = x0 + x1, ss = x0 * x0 + x1 * x1;
    for (int m = 1; m < 64; m <<= 1){ s += __shfl_xor(s, m); ss += __shfl_xor(ss, m); }
    float mean = s * (1.0f / EMBED);
    float var  = ss * (1.0f / EMBED) - mean * mean;
    float rs   = rsqrtf(var + 1e-5f);
    float g0 = loadf(g, lane * 2, isf32), g1 = loadf(g, lane * 2 + 1, isf32);
    float b0 = loadf(b, lane * 2, isf32), b1v = loadf(b, lane * 2 + 1, isf32);
    float y0 = (x0 - mean) * rs * g0 + b0;
    float y1 = (x1 - mean) * rs * g1 + b1v;
    *(uint32_t*)(h + (size_t)node * EMBED + lane * 2) = pack2(y0, y1);
}

// ---------------- Weight + bias prepack (bf16, MFMA B-frag order) ----------------
__global__ __launch_bounds__(256) void prepack_kernel(
    const void* __restrict__ W1, const void* __restrict__ W2, const void* __restrict__ Wt,
    const void* __restrict__ b1, const void* __restrict__ b2, const void* __restrict__ bt,
    unsigned short* __restrict__ W1p, unsigned short* __restrict__ W2p,
    unsigned short* __restrict__ Wtp, unsigned short* __restrict__ bpk,
    const int* __restrict__ flags)
{
    int isf32 = flags[0];
    int t = blockIdx.x * blockDim.x + threadIdx.x;
    if (t < 32768){            // W1: [128][256], 16 ntiles x 4 k32
        int j = t & 7, lane = (t >> 3) & 63, k32 = (t >> 9) & 3, nt = t >> 11;
        int k = k32 * 32 + (lane >> 4) * 8 + j, n = nt * 16 + (lane & 15);
        W1p[t] = f2bf(loadf(W1, (size_t)k * HIDDEN + n, isf32));
    } else if (t < 65536){     // W2: [256][128], 8 ntiles x 8 k32
        int t2 = t - 32768;
        int j = t2 & 7, lane = (t2 >> 3) & 63, k32 = (t2 >> 9) & 7, nt = t2 >> 12;
        int k = k32 * 32 + (lane >> 4) * 8 + j, n = nt * 16 + (lane & 15);
        W2p[t2] = f2bf(loadf(W2, (size_t)k * EMBED + n, isf32));
    } else if (t < 81920){     // Wt: [128][128], 8 ntiles x 4 k32
        int t3 = t - 65536;
        int j = t3 & 7, lane = (t3 >> 3) & 63, k32 = (t3 >> 9) & 3, nt = t3 >> 11;
        int k = k32 * 32 + (lane >> 4) * 8 + j, n = nt * 16 + (lane & 15);
        Wtp[t3] = f2bf(loadf(Wt, (size_t)k * EMBED + n, isf32));
    } else if (t < 82176){
        int i = t - 81920; bpk[i] = f2bf(loadf(b1, i, isf32));
    } else if (t < 82304){
        int i = t - 82176; bpk[256 + i] = f2bf(loadf(b2, i, isf32));
    } else if (t < 82432){
        int i = t - 82304; bpk[384 + i] = f2bf(loadf(bt, i, isf32));
    }
}

// ---------------- Edge MLP: block = 64-edge tile, column-split waves ----------------
// Wave w: GEMM1 n-tiles {4w..4w+3}, GEMM2 n-tiles {2w,2w+1}; B-frags in registers.
__global__ __launch_bounds__(256, 3) void edge_kernel(
    const void* __restrict__ ee, const unsigned short* __restrict__ h,
    const int* __restrict__ eidx, int E,
    const unsigned short* __restrict__ W1p, const unsigned short* __restrict__ W2p,
    const unsigned short* __restrict__ bpk,
    float* __restrict__ agg, const int* __restrict__ flags)
{
    __shared__ __align__(16) unsigned short sbuf[64][136]; // silu(s): 64 x 128 (17.4 KB)
    __shared__ __align__(16) unsigned short tbuf[64][264]; // silu(t): 64 x 256 (33.8 KB)
    __shared__ int cbuf[64], nbuf[64];
    int isf32 = flags[0], is64 = flags[1];
    int wave = threadIdx.x >> 6, lane = threadIdx.x & 63;
    int quad = lane >> 4, l16 = lane & 15;
    int ebase = blockIdx.x * 64;
    int colg = l16 * 8;

    // ---- stage silu(edge + h_c + h_n) -> sbuf rows [wave*16 .. wave*16+15]
    #pragma unroll
    for (int i = 0; i < 4; i++){
        int row = wave * 16 + i * 4 + quad;
        int e = ebase + row; if (e >= E) e = E - 1;
        int c = idx_c(eidx, e, is64), n = idx_n(eidx, e, E, is64);
        if (l16 == 0){ cbuf[row] = c; nbuf[row] = n; }
        float fe[8];
        load8f(ee, (size_t)e * EMBED + colg, isf32, fe);
        uint4 vc = *(const uint4*)(h + (size_t)c * EMBED + colg);
        uint4 vn = *(const uint4*)(h + (size_t)n * EMBED + colg);
        uint32_t pc[4] = {vc.x, vc.y, vc.z, vc.w};
        uint32_t pn[4] = {vn.x, vn.y, vn.z, vn.w};
        uint32_t o[4];
        #pragma unroll
        for (int q = 0; q < 4; q++){
            float a0 = fe[2*q]   + lo_f(pc[q]) + lo_f(pn[q]);
            float a1 = fe[2*q+1] + hi_f(pc[q]) + hi_f(pn[q]);
            o[q] = pack2(silu_f(a0), silu_f(a1));
        }
        *(uint4*)&sbuf[row][colg] = make_uint4(o[0], o[1], o[2], o[3]);
    }
    __syncthreads();

    // ---- GEMM1: this wave computes cols [64w .. 64w+63] for all 64 edges
    {
        int ntb = wave * 4;
        v8bf bw[4][4];
        float bias[4];
        #pragma unroll
        for (int j = 0; j < 4; j++){
            bias[j] = bf2f(bpk[(ntb + j) * 16 + l16]);
            #pragma unroll
            for (int k32 = 0; k32 < 4; k32++)
                bw[j][k32] = *(const v8bf*)(W1p + ((size_t)((ntb + j) * 4 + k32) * 64 + lane) * 8);
        }
        #pragma unroll
        for (int rt = 0; rt < 4; rt++){
            v8bf a[4];
            #pragma unroll
            for (int k32 = 0; k32 < 4; k32++)
                a[k32] = *(const v8bf*)&sbuf[rt * 16 + l16][k32 * 32 + quad * 8];
            v4f acc[4];
            #pragma unroll
            for (int j = 0; j < 4; j++) acc[j] = (v4f){bias[j], bias[j], bias[j], bias[j]};
            #pragma unroll
            for (int k32 = 0; k32 < 4; k32++)
                #pragma unroll
                for (int j = 0; j < 4; j++)
                    acc[j] = __builtin_amdgcn_mfma_f32_16x16x32_bf16(a[k32], bw[j][k32], acc[j], 0, 0, 0);
            #pragma unroll
            for (int j = 0; j < 4; j++)
                #pragma unroll
                for (int r = 0; r < 4; r++)
                    tbuf[rt * 16 + quad * 4 + r][(ntb + j) * 16 + l16] = f2bf(silu_f(acc[j][r]));
        }
    }
    __syncthreads();

    // ---- GEMM2: this wave computes cols [32w .. 32w+31]; epilogue msg->atomic agg
    {
        int ntb = wave * 2;
        v8bf bw[2][8];
        float bias[2];
        #pragma unroll
        for (int j = 0; j < 2; j++){
            bias[j] = bf2f(bpk[256 + (ntb + j) * 16 + l16]);
            #pragma unroll
            for (int k32 = 0; k32 < 8; k32++)
                bw[j][k32] = *(const v8bf*)(W2p + ((size_t)((ntb + j) * 8 + k32) * 64 + lane) * 8);
        }
        #pragma unroll
        for (int rt = 0; rt < 4; rt++){
            v8bf a[8];
            #pragma unroll
            for (int k32 = 0; k32 < 8; k32++)
                a[k32] = *(const v8bf*)&tbuf[rt * 16 + l16][k32 * 32 + quad * 8];
            v4f acc[2];
            #pragma unroll
            for (int j = 0; j < 2; j++) acc[j] = (v4f){bias[j], bias[j], bias[j], bias[j]};
            #pragma unroll
            for (int k32 = 0; k32 < 8; k32++)
                #pragma unroll
                for (int j = 0; j < 2; j++)
                    acc[j] = __builtin_amdgcn_mfma_f32_16x16x32_bf16(a[k32], bw[j][k32], acc[j], 0, 0, 0);
            #pragma unroll
            for (int j = 0; j < 2; j++){
                int col = (ntb + j) * 16 + l16;
                #pragma unroll
                for (int r = 0; r < 4; r++){
                    int row = rt * 16 + quad * 4 + r;
                    int e = ebase + row;
                    if (e < E){
                        int c = cbuf[row], n = nbuf[row];
                        float hn = bf2f(h[(size_t)n * EMBED + col]);
                        atomicAdd(&agg[(size_t)c * EMBED + col], acc[j][r] * hn);
                    }
                }
            }
        }
    }
}

// ---------------- Node output: out = silu(h + agg) @ Wt + bt ----------------
__global__ __launch_bounds__(256) void node_out_kernel(
    const unsigned short* __restrict__ h, const float* __restrict__ agg,
    const unsigned short* __restrict__ Wtp, const unsigned short* __restrict__ bpk,
    void* __restrict__ out, int N, const int* __restrict__ flags)
{
    __shared__ __align__(16) unsigned short ubuf[4][16][136];
    int isf32 = flags[0];
    int wave = threadIdx.x >> 6, lane = threadIdx.x & 63;
    int quad = lane >> 4, l16 = lane & 15;
    int nbase = (blockIdx.x * 4 + wave) * 16;
    int colg = l16 * 8;
    #pragma unroll
    for (int i = 0; i < 4; i++){
        int row = i * 4 + quad;
        int node = nbase + row; int nn = node < N ? node : N - 1;
        uint4 vh = *(const uint4*)(h + (size_t)nn * EMBED + colg);
        float4 a0 = *(const float4*)(agg + (size_t)nn * EMBED + colg);
        float4 a1 = *(const float4*)(agg + (size_t)nn * EMBED + colg + 4);
        uint32_t ph[4] = {vh.x, vh.y, vh.z, vh.w};
        float af[8] = {a0.x, a0.y, a0.z, a0.w, a1.x, a1.y, a1.z, a1.w};
        uint32_t o[4];
        #pragma unroll
        for (int q = 0; q < 4; q++){
            float u0 = lo_f(ph[q]) + af[2 * q];
            float u1 = hi_f(ph[q]) + af[2 * q + 1];
            o[q] = pack2(silu_f(u0), silu_f(u1));
        }
        *(uint4*)&ubuf[wave][row][colg] = make_uint4(o[0], o[1], o[2], o[3]);
    }
    __syncthreads();
    for (int nt = 0; nt < 8; nt++){
        int col = nt * 16 + l16;
        float bc = bf2f(bpk[384 + col]);
        v4f acc = {bc, bc, bc, bc};
        #pragma unroll
        for (int k32 = 0; k32 < 4; k32++){
            v8bf a = *(const v8bf*)&ubuf[wave][l16][k32 * 32 + quad * 8];
            v8bf b = *(const v8bf*)(Wtp + ((size_t)(nt * 4 + k32) * 64 + lane) * 8);
            acc = __builtin_amdgcn_mfma_f32_16x16x32_bf16(a, b, acc, 0, 0, 0);
        }
        #pragma unroll
        for (int r = 0; r < 4; r++){
            int node = nbase + quad * 4 + r;
            if (node < N){
                if (isf32) ((float*)out)[(size_t)node * EMBED + col] = acc[r];
                else ((unsigned short*)out)[(size_t)node * EMBED + col] = f2bf(acc[r]);
            }
        }
    }
}

extern "C" void kernel_launch(void* const* d_in, const int* in_sizes, int n_in,
                              void* d_out, int out_size, void* d_ws, size_t ws_size,
                              hipStream_t stream)
{
    const void* ne = d_in[0];
    const void* ee = d_in[1];
    const int* eidx = (const int*)d_in[2];
    const void* g  = d_in[3];
    const void* be = d_in[4];
    const void* W1 = d_in[5];
    const void* b1 = d_in[6];
    const void* W2 = d_in[7];
    const void* b2 = d_in[8];
    const void* Wt = d_in[9];
    const void* bt = d_in[10];
    int N = in_sizes[0] / EMBED;   // 50000
    int E = in_sizes[2] / 2;       // 640000

    char* ws = (char*)d_ws;
    int* flags = (int*)ws;
    unsigned short* h = (unsigned short*)(ws + 256);
    size_t off1 = 256 + (size_t)N * EMBED * 2;
    float* agg = (float*)(ws + off1);
    size_t off2 = off1 + (size_t)N * EMBED * 4;
    unsigned short* W1p = (unsigned short*)(ws + off2);
    unsigned short* W2p = W1p + 32768;
    unsigned short* Wtp = W2p + 32768;
    unsigned short* bpk = Wtp + 16384;

    probe_kernel<<<1, 256, 0, stream>>>((const unsigned short*)ne, eidx, flags);
    hipMemsetAsync(agg, 0, (size_t)N * EMBED * sizeof(float), stream);
    prepack_kernel<<<(82432 + 255) / 256, 256, 0, stream>>>(W1, W2, Wt, b1, b2, bt,
                                                            W1p, W2p, Wtp, bpk, flags);
    ln_kernel<<<(N + 3) / 4, 256, 0, stream>>>(ne, g, be, h, N, flags);
    edge_kernel<<<(E + 63) / 64, 256, 0, stream>>>(ee, h, eidx, E,
                                                   W1p, W2p, bpk, agg, flags);
    node_out_kernel<<<(N + 63) / 64, 256, 0, stream>>>(h, agg, Wtp, bpk,
                                                       d_out, N, flags);
}